// Round 2
// baseline (255.574 us; speedup 1.0000x reference)
//
#include <hip/hip_runtime.h>

// out[b, j] = p_cls[b, j>>8] * p_subcls[b, j>>6] * p_maingrp[b, j>>5]
//           * p_subgrp[b, j>>3] * p_fi[b, j]
// All index maps from the reference collapse to uniform divisions:
//   IDX4 = j/8, IDX3 = j/32, IDX2 = j/64, IDX1 = j/256.
// Pure streaming multiply: memory-bound (~292 MB compulsory traffic).

__global__ __launch_bounds__(256) void hier_mul_kernel(
        const float* __restrict__ p_cls,      // [B, 8]
        const float* __restrict__ p_subcls,   // [B, 32]
        const float* __restrict__ p_maingrp,  // [B, 64]
        const float* __restrict__ p_subgrp,   // [B, 256]
        const float* __restrict__ p_fi,       // [B, 2048]
        float* __restrict__ out,              // [B, 2048]
        int total4) {                         // B * 512 float4 items
    const int stride = gridDim.x * blockDim.x;
    for (int i = blockIdx.x * blockDim.x + threadIdx.x; i < total4; i += stride) {
        const int row = i >> 9;        // 512 float4 per row (2048 floats)
        const int j   = (i & 511) << 2; // leaf index of .x element, 0..2044
        // One scalar multiplier per aligned float4: j..j+3 share j>>3 (and
        // hence all coarser ancestors) because j is a multiple of 4.
        const float s = p_cls    [(row << 3) + (j >> 8)]
                      * p_subcls [(row << 5) + (j >> 6)]
                      * p_maingrp[(row << 6) + (j >> 5)]
                      * p_subgrp [(row << 8) + (j >> 3)];
        const float4 fi = reinterpret_cast<const float4*>(p_fi)[i];
        float4 o;
        o.x = fi.x * s;
        o.y = fi.y * s;
        o.z = fi.z * s;
        o.w = fi.w * s;
        reinterpret_cast<float4*>(out)[i] = o;
    }
}

extern "C" void kernel_launch(void* const* d_in, const int* in_sizes, int n_in,
                              void* d_out, int out_size, void* d_ws, size_t ws_size,
                              hipStream_t stream) {
    const float* p_cls     = (const float*)d_in[0];
    const float* p_subcls  = (const float*)d_in[1];
    const float* p_maingrp = (const float*)d_in[2];
    const float* p_subgrp  = (const float*)d_in[3];
    const float* p_fi      = (const float*)d_in[4];
    float* out = (float*)d_out;

    const int total4 = in_sizes[4] / 4;           // B * 512
    const int block = 256;
    int grid = (total4 + block - 1) / block;
    if (grid > 2048) grid = 2048;                 // grid-stride the rest

    hier_mul_kernel<<<grid, block, 0, stream>>>(
        p_cls, p_subcls, p_maingrp, p_subgrp, p_fi, out, total4);
}

// Round 4
// 250.161 us; speedup vs baseline: 1.0216x; 1.0216x over previous
//
#include <hip/hip_runtime.h>

// out[b, j] = p_cls[b, j>>8] * p_subcls[b, j>>6] * p_maingrp[b, j>>5]
//           * p_subgrp[b, j>>3] * p_fi[b, j]
// Memory-bound streaming multiply. Round-2 post-mortem: grid-stride loop with
// per-iteration vmcnt(0) drain capped us at 2.5 TB/s (40% of achievable).
// This version: exact grid, one block per row, one thread per 8-leaf subgroup
// -> 6 loads issued back-to-back, single wait, 2 nontemporal stores. More
// bytes in flight per wave, no loop serialization.
// Note: __builtin_nontemporal_* needs a clang vector type, not HIP float4.

typedef float f32x4 __attribute__((ext_vector_type(4)));

__global__ __launch_bounds__(256) void hier_mul_kernel(
        const float* __restrict__ p_cls,      // [B, 8]
        const float* __restrict__ p_subcls,   // [B, 32]
        const float* __restrict__ p_maingrp,  // [B, 64]
        const float* __restrict__ p_subgrp,   // [B, 256]
        const float* __restrict__ p_fi,       // [B, 2048]
        float* __restrict__ out) {            // [B, 2048]
    const int row = blockIdx.x;
    const int t   = threadIdx.x;              // subgroup index 0..255

    // float4 index of this thread's first quad (2 quads = 8 leaves)
    const int i0 = (row << 9) + (t << 1);
    const f32x4* __restrict__ fi4 = reinterpret_cast<const f32x4*>(p_fi);
    f32x4* out4 = reinterpret_cast<f32x4*>(out);

    // All 6 loads are independent -> compiler batches them before one waitcnt.
    const f32x4 a = __builtin_nontemporal_load(fi4 + i0);
    const f32x4 b = __builtin_nontemporal_load(fi4 + i0 + 1);
    const float c0 = p_cls    [(row << 3) + (t >> 5)];   // 2 distinct/wave (broadcast)
    const float c1 = p_subcls [(row << 5) + (t >> 3)];   // 8 distinct/wave
    const float c2 = p_maingrp[(row << 6) + (t >> 2)];   // 16 distinct/wave
    const float c3 = p_subgrp [(row << 8) + t];          // fully coalesced

    const float s = c0 * c1 * c2 * c3;

    const f32x4 oa = a * s;
    const f32x4 ob = b * s;
    __builtin_nontemporal_store(oa, out4 + i0);
    __builtin_nontemporal_store(ob, out4 + i0 + 1);
}

extern "C" void kernel_launch(void* const* d_in, const int* in_sizes, int n_in,
                              void* d_out, int out_size, void* d_ws, size_t ws_size,
                              hipStream_t stream) {
    const float* p_cls     = (const float*)d_in[0];
    const float* p_subcls  = (const float*)d_in[1];
    const float* p_maingrp = (const float*)d_in[2];
    const float* p_subgrp  = (const float*)d_in[3];
    const float* p_fi      = (const float*)d_in[4];
    float* out = (float*)d_out;

    const int rows = in_sizes[4] / 2048;      // B
    hier_mul_kernel<<<rows, 256, 0, stream>>>(
        p_cls, p_subcls, p_maingrp, p_subgrp, p_fi, out);
}